// Round 1
// baseline (85.177 us; speedup 1.0000x reference)
//
#include <hip/hip_runtime.h>

#define NG 14      // groups
#define NCH 112    // total channels (14*8)
#define FEAT_STRIDE 132

__global__ __launch_bounds__(256) void ae_kernel(
    const float* __restrict__ x,            // [N,14,8,8]
    const int*   __restrict__ keys,         // [N]
    const float* __restrict__ conv_mask,    // [3,3]
    const float* __restrict__ enc_conv_w,   // [16,112,1,3,3]
    const float* __restrict__ enc_dense_w,  // [16,14,8,128]
    const float* __restrict__ enc_dense_b,  // [16,14,8]
    const float* __restrict__ dec_dense_w,  // [16,14,128,8]
    const float* __restrict__ dec_dense_b,  // [16,14,128]
    const float* __restrict__ dec_tconv_w,  // [16,112,1,3,3]
    const float* __restrict__ dec_tconv_b,  // [16,14]
    float* __restrict__ out)                // [N,14,8,8]
{
    const int n = blockIdx.x;
    const int t = threadIdx.x;
    const int k = keys[n];

    __shared__ float xs[NG * 64];              // 896
    __shared__ float wcs[NCH * 9];             // masked enc conv weights
    __shared__ float wts[NCH * 9];             // tconv weights (unflipped)
    __shared__ float feat[NG * FEAT_STRIDE];   // feat, later reused for y
    __shared__ float zs[NG * 8];               // 112

    // ---- stage x (coalesced float4) ----
    const float4* xg = (const float4*)(x + (size_t)n * 896);
    if (t < 224) ((float4*)xs)[t] = xg[t];
    // ---- stage conv weights (mask applied) + tconv weights ----
    for (int i = t; i < 2016; i += 256) {
        if (i < 1008) {
            wcs[i] = enc_conv_w[(size_t)k * 1008 + i] * conv_mask[i % 9];
        } else {
            int j = i - 1008;
            wts[j] = dec_tconv_w[(size_t)k * 1008 + j];
        }
    }
    __syncthreads();

    // ---- step 1: masked conv (SAME) + ReLU + 2x2 maxpool -> feat[g][c*16+pi*4+pj]
    for (int idx = t; idx < 1792; idx += 256) {
        const int cc = idx >> 4;       // 0..111
        const int p  = idx & 15;       // pooled pixel
        const int pi = p >> 2, pj = p & 3;
        const int g  = cc >> 3;
        const float* xrow = xs + g * 64;
        const float* w = wcs + cc * 9;
        float mx = 0.f;                // ReLU floor (max of relus == relu of max)
        #pragma unroll
        for (int a = 0; a < 2; ++a) {
            #pragma unroll
            for (int b = 0; b < 2; ++b) {
                const int ii = 2 * pi + a, jj = 2 * pj + b;
                float acc = 0.f;
                #pragma unroll
                for (int di = 0; di < 3; ++di) {
                    const int yy = ii + di - 1;
                    if (yy < 0 || yy > 7) continue;
                    #pragma unroll
                    for (int dj = 0; dj < 3; ++dj) {
                        const int xx = jj + dj - 1;
                        if (xx < 0 || xx > 7) continue;
                        acc += w[di * 3 + dj] * xrow[yy * 8 + xx];
                    }
                }
                mx = fmaxf(mx, acc);
            }
        }
        feat[g * FEAT_STRIDE + (cc & 7) * 16 + p] = mx;
    }
    __syncthreads();

    // ---- step 2: z[g][o] = relu(encW[g,o,:] . feat[g,:] + b) ----
    if (t < 112) {
        const int g = t >> 3, o = t & 7;
        const float4* wrow = (const float4*)(enc_dense_w + ((size_t)(k * NG + g) * 8 + o) * 128);
        const float* frow = feat + g * FEAT_STRIDE;
        float acc = enc_dense_b[(k * NG + g) * 8 + o];
        #pragma unroll
        for (int q = 0; q < 32; ++q) {
            const float4 w4 = wrow[q];
            acc += w4.x * frow[q * 4 + 0] + w4.y * frow[q * 4 + 1]
                 + w4.z * frow[q * 4 + 2] + w4.w * frow[q * 4 + 3];
        }
        zs[t] = fmaxf(acc, 0.f);
    }
    __syncthreads();

    // ---- step 3: y[g][f] = relu(decW[g,f,:] . z[g,:] + b)  (overwrites feat) ----
    for (int idx = t; idx < 1792; idx += 256) {
        const int g = idx >> 7, f = idx & 127;
        const float* w = dec_dense_w + ((size_t)(k * NG + g) * 128 + f) * 8;
        const float* zr = zs + g * 8;
        float acc = dec_dense_b[(k * NG + g) * 128 + f];
        #pragma unroll
        for (int o = 0; o < 8; ++o) acc += w[o] * zr[o];
        feat[g * FEAT_STRIDE + f] = fmaxf(acc, 0.f);
    }
    __syncthreads();

    // ---- step 4: grouped ConvTranspose2d(stride2,pad1,outpad1) + bias + ReLU ----
    // direct form: out[oi,oj] += w[c,ki,kj] * y[c,i,j] where 2i+ki==oi+1, 2j+kj==oj+1
    for (int idx = t; idx < 896; idx += 256) {
        const int g = idx >> 6, pix = idx & 63;
        const int oi = pix >> 3, oj = pix & 7;
        const float* yrow = feat + g * FEAT_STRIDE;  // y[g][c*16+i*4+j]
        const float* w = wts + (g * 8) * 9;
        float acc = dec_tconv_b[k * NG + g];
        #pragma unroll
        for (int ki = 0; ki < 3; ++ki) {
            const int ni = oi + 1 - ki;
            if (ni & 1) continue;
            const int i = ni >> 1;
            if (i < 0 || i > 3) continue;
            #pragma unroll
            for (int kj = 0; kj < 3; ++kj) {
                const int nj = oj + 1 - kj;
                if (nj & 1) continue;
                const int j = nj >> 1;
                if (j < 0 || j > 3) continue;
                #pragma unroll
                for (int c = 0; c < 8; ++c) {
                    acc += w[c * 9 + ki * 3 + kj] * yrow[c * 16 + i * 4 + j];
                }
            }
        }
        out[(size_t)n * 896 + idx] = fmaxf(acc, 0.f);
    }
}

extern "C" void kernel_launch(void* const* d_in, const int* in_sizes, int n_in,
                              void* d_out, int out_size, void* d_ws, size_t ws_size,
                              hipStream_t stream) {
    const float* x            = (const float*)d_in[0];
    const int*   keys         = (const int*)d_in[1];
    const float* conv_mask    = (const float*)d_in[2];
    const float* enc_conv_w   = (const float*)d_in[3];
    const float* enc_dense_w  = (const float*)d_in[4];
    const float* enc_dense_b  = (const float*)d_in[5];
    const float* dec_dense_w  = (const float*)d_in[6];
    const float* dec_dense_b  = (const float*)d_in[7];
    const float* dec_tconv_w  = (const float*)d_in[8];
    const float* dec_tconv_b  = (const float*)d_in[9];
    float* out = (float*)d_out;

    const int N = in_sizes[0] / (NG * 64);   // 4096
    ae_kernel<<<dim3(N), dim3(256), 0, stream>>>(
        x, keys, conv_mask, enc_conv_w, enc_dense_w, enc_dense_b,
        dec_dense_w, dec_dense_b, dec_tconv_w, dec_tconv_b, out);
}

// Round 2
// 65.408 us; speedup vs baseline: 1.3022x; 1.3022x over previous
//
#include <hip/hip_runtime.h>

#define NG 14      // groups (input channels)
#define NCH 112    // conv output channels (14*8)
#define FEAT_STRIDE 136
#define XROW 12
#define XPAD_CH 144   // 12 rows x 12 cols per group, padded, float4-aligned rows

__global__ __launch_bounds__(256, 4) void ae_kernel(
    const float* __restrict__ x,            // [N,14,8,8]
    const int*   __restrict__ keys,         // [N]
    const float* __restrict__ conv_mask,    // [3,3]
    const float* __restrict__ enc_conv_w,   // [16,112,1,3,3]
    const float* __restrict__ enc_dense_w,  // [16,14,8,128]
    const float* __restrict__ enc_dense_b,  // [16,14,8]
    const float* __restrict__ dec_dense_w,  // [16,14,128,8]
    const float* __restrict__ dec_dense_b,  // [16,14,128]
    const float* __restrict__ dec_tconv_w,  // [16,112,1,3,3]
    const float* __restrict__ dec_tconv_b,  // [16,14]
    float* __restrict__ out)                // [N,14,8,8]
{
    const int n = blockIdx.x;
    const int t = threadIdx.x;
    const int k = keys[n];

    __shared__ float xsp[NG * XPAD_CH];        // 2016 padded input
    __shared__ float wcs[NCH * 9];             // masked enc conv weights
    __shared__ float wts[NCH * 9];             // tconv weights (unflipped)
    __shared__ float feat[NG * FEAT_STRIDE];   // feat, later reused for y
    __shared__ float zs[NG * 8];

    // ---- zero the padded input tile (float4) ----
    {
        float4* xz = (float4*)xsp;
        #pragma unroll
        for (int i = 0; i < 2; ++i) {
            int j = t + i * 256;
            if (j < NG * XPAD_CH / 4) xz[j] = make_float4(0.f, 0.f, 0.f, 0.f);
        }
    }
    __syncthreads();   // zero-writes overlap interior fill below

    // ---- fill interior + stage weights ----
    for (int i = t; i < 896; i += 256) {
        const float v = x[(size_t)n * 896 + i];
        const int g = i >> 6, rem = i & 63, r = rem >> 3, c = rem & 7;
        xsp[g * XPAD_CH + (r + 1) * XROW + (c + 1)] = v;
    }
    for (int i = t; i < 2016; i += 256) {
        if (i < 1008) wcs[i] = enc_conv_w[(size_t)k * 1008 + i] * conv_mask[i % 9];
        else          wts[i - 1008] = dec_tconv_w[(size_t)k * 1008 + (i - 1008)];
    }
    __syncthreads();

    // ---- step 1: masked conv (7 live taps) + ReLU + 2x2 maxpool ----
    // thread u<224: u = cc*2+h; computes pooled rows {2h, 2h+1} for channel cc
    if (t < 224) {
        const int cc = t >> 1, h = t & 1, g = cc >> 3;
        const float* w = wcs + cc * 9;
        const float w00 = w[0], w01 = w[1], w10 = w[3], w11 = w[4],
                    w12 = w[5], w21 = w[7], w22 = w[8];
        const float* xb = xsp + g * XPAD_CH;
        float* fout = feat + g * FEAT_STRIDE + (cc & 7) * 16;
        #pragma unroll
        for (int prl = 0; prl < 2; ++prl) {
            const int pr = 2 * h + prl;         // pooled row 0..3
            const float* rbase = xb + 2 * pr * XROW;  // padded rows 2pr..2pr+3
            #pragma unroll
            for (int pc = 0; pc < 4; ++pc) {
                float mx = 0.f;
                #pragma unroll
                for (int rl = 0; rl < 2; ++rl) {
                    #pragma unroll
                    for (int cl = 0; cl < 2; ++cl) {
                        const int cx = 2 * pc + cl;   // conv col 0..7; padded cols cx..cx+2
                        const float* r0 = rbase + rl * XROW;
                        const float s = r0[cx] * w00 + r0[cx + 1] * w01
                                      + r0[XROW + cx] * w10 + r0[XROW + cx + 1] * w11
                                      + r0[XROW + cx + 2] * w12
                                      + r0[2 * XROW + cx + 1] * w21
                                      + r0[2 * XROW + cx + 2] * w22;
                        mx = fmaxf(mx, s);
                    }
                }
                fout[pr * 4 + pc] = mx;
            }
        }
    }
    __syncthreads();

    // ---- step 2: z[g][o] = relu(encW . feat + b), 2 threads per output ----
    if (t < 224) {
        const int g = t >> 4, o = (t >> 1) & 7, hh = t & 1;
        const float4* frow = (const float4*)(feat + g * FEAT_STRIDE + hh * 64);
        const float4* wrow = (const float4*)(enc_dense_w
                              + ((size_t)(k * NG + g) * 8 + o) * 128 + hh * 64);
        float acc = 0.f;
        #pragma unroll
        for (int q = 0; q < 16; ++q) {
            const float4 w4 = wrow[q];
            const float4 f4 = frow[q];
            acc += w4.x * f4.x + w4.y * f4.y + w4.z * f4.z + w4.w * f4.w;
        }
        const float other = __shfl_xor(acc, 1);
        if (hh == 0) {
            zs[g * 8 + o] = fmaxf(acc + other + enc_dense_b[(k * NG + g) * 8 + o], 0.f);
        }
    }
    __syncthreads();

    // ---- step 3: y[g][f] = relu(decW . z + b)  (overwrites feat) ----
    for (int idx = t; idx < 1792; idx += 256) {
        const int g = idx >> 7, f = idx & 127;
        const float4* w4 = (const float4*)(dec_dense_w + ((size_t)(k * NG + g) * 128 + f) * 8);
        const float4 wa = w4[0], wb = w4[1];
        const float* zr = zs + g * 8;
        float acc = dec_dense_b[(k * NG + g) * 128 + f];
        acc += wa.x * zr[0] + wa.y * zr[1] + wa.z * zr[2] + wa.w * zr[3];
        acc += wb.x * zr[4] + wb.y * zr[5] + wb.z * zr[6] + wb.w * zr[7];
        feat[g * FEAT_STRIDE + f] = fmaxf(acc, 0.f);
    }
    __syncthreads();

    // ---- step 4: grouped ConvTranspose2d(stride2,pad1,outpad1) + bias + ReLU ----
    // out[oi,oj] = sum w[c,ki,kj]*y[c,i,j] where 2i+ki==oi+1, 2j+kj==oj+1
    for (int idx = t; idx < 896; idx += 256) {
        const int g = idx >> 6, pix = idx & 63;
        const int oi = pix >> 3, oj = pix & 7;
        // valid (i,ki) taps for this oi (1 or 2)
        int nti = 1, iA, kiA, iB = 0, kiB = 0;
        if ((oi & 1) == 0) { iA = oi >> 1; kiA = 1; }
        else { iA = (oi - 1) >> 1; kiA = 2; if (oi < 7) { nti = 2; iB = (oi + 1) >> 1; kiB = 0; } }
        int ntj = 1, jA, kjA, jB = 0, kjB = 0;
        if ((oj & 1) == 0) { jA = oj >> 1; kjA = 1; }
        else { jA = (oj - 1) >> 1; kjA = 2; if (oj < 7) { ntj = 2; jB = (oj + 1) >> 1; kjB = 0; } }

        const float* yg = feat + g * FEAT_STRIDE;
        const float* wg = wts + g * 72;
        float acc = dec_tconv_b[k * NG + g];
        for (int a_ = 0; a_ < nti; ++a_) {
            const int i  = a_ ? iB : iA;
            const int ki = a_ ? kiB : kiA;
            for (int b_ = 0; b_ < ntj; ++b_) {
                const int j  = b_ ? jB : jA;
                const int kj = b_ ? kjB : kjA;
                const float* wp = wg + ki * 3 + kj;
                const float* yp = yg + i * 4 + j;
                #pragma unroll
                for (int c = 0; c < 8; ++c) acc += wp[c * 9] * yp[c * 16];
            }
        }
        out[(size_t)n * 896 + idx] = fmaxf(acc, 0.f);
    }
}

extern "C" void kernel_launch(void* const* d_in, const int* in_sizes, int n_in,
                              void* d_out, int out_size, void* d_ws, size_t ws_size,
                              hipStream_t stream) {
    const float* x            = (const float*)d_in[0];
    const int*   keys         = (const int*)d_in[1];
    const float* conv_mask    = (const float*)d_in[2];
    const float* enc_conv_w   = (const float*)d_in[3];
    const float* enc_dense_w  = (const float*)d_in[4];
    const float* enc_dense_b  = (const float*)d_in[5];
    const float* dec_dense_w  = (const float*)d_in[6];
    const float* dec_dense_b  = (const float*)d_in[7];
    const float* dec_tconv_w  = (const float*)d_in[8];
    const float* dec_tconv_b  = (const float*)d_in[9];
    float* out = (float*)d_out;

    const int N = in_sizes[0] / (NG * 64);   // 4096
    ae_kernel<<<dim3(N), dim3(256), 0, stream>>>(
        x, keys, conv_mask, enc_conv_w, enc_dense_w, enc_dense_b,
        dec_dense_w, dec_dense_b, dec_tconv_w, dec_tconv_b, out);
}